// Round 19
// baseline (1999.141 us; speedup 1.0000x reference)
//
#include <hip/hip_runtime.h>
#include <hip/hip_bf16.h>

typedef __bf16 bf16_t;
typedef bf16_t bf16x8 __attribute__((ext_vector_type(8)));
typedef bf16_t bf16x4 __attribute__((ext_vector_type(4)));
typedef float  f32x4  __attribute__((ext_vector_type(4)));

// ---------------------------------------------------------------------------
// global -> LDS async copy, 16B per lane. lds base must be wave-uniform.
// ---------------------------------------------------------------------------
__device__ __forceinline__ void gload16(const void* g, void* l) {
    __builtin_amdgcn_global_load_lds(
        (const __attribute__((address_space(1))) unsigned int*)g,
        (__attribute__((address_space(3))) unsigned int*)l, 16, 0, 0);
}

__device__ __forceinline__ void drain_and_barrier() {
    __builtin_amdgcn_sched_barrier(0);
    asm volatile("s_waitcnt vmcnt(0)" ::: "memory");
    __builtin_amdgcn_s_barrier();
    __builtin_amdgcn_sched_barrier(0);
}

// ---------------------------------------------------------------------------
// Embedding: h[b,s,:] = emb[x[b,s],:] + posemb[s,:]
// ---------------------------------------------------------------------------
__global__ void embed_kernel(const int* __restrict__ x,
                             const float* __restrict__ emb,
                             const float* __restrict__ pos,
                             float* __restrict__ h,
                             int S, int D, int total)
{
    int i = blockIdx.x * blockDim.x + threadIdx.x;
    if (i >= total) return;
    int d  = i % D;
    int bs = i / D;
    int s  = bs % S;
    h[i] = emb[(long long)x[bs] * D + d] + pos[(long long)s * D + d];
}

// ---------------------------------------------------------------------------
// elementwise f32 -> bf16 (vectorized by 4)
// ---------------------------------------------------------------------------
__global__ void convert_bf16(const float* __restrict__ in, bf16_t* __restrict__ out, int n4)
{
    int i = blockIdx.x * blockDim.x + threadIdx.x;
    for (; i < n4; i += gridDim.x * blockDim.x) {
        float4 v = ((const float4*)in)[i];
        bf16_t* o = out + (size_t)i * 4;
        o[0] = (bf16_t)v.x; o[1] = (bf16_t)v.y; o[2] = (bf16_t)v.z; o[3] = (bf16_t)v.w;
    }
}

// ---------------------------------------------------------------------------
// Batched transpose + bf16 convert: out[z][n][k] = (bf16) in[z][k][n]
// ---------------------------------------------------------------------------
__global__ __launch_bounds__(256) void transpose_to_bf16(
    const float* __restrict__ in, bf16_t* __restrict__ out, int K, int N)
{
    const float* ip = in  + (size_t)blockIdx.z * K * N;
    bf16_t*      op = out + (size_t)blockIdx.z * K * N;
    __shared__ float t[32][33];
    const int n0 = blockIdx.x * 32, k0 = blockIdx.y * 32;
    const int tx = threadIdx.x, ty = threadIdx.y;
#pragma unroll
    for (int u = 0; u < 4; ++u)
        t[ty + u * 8][tx] = ip[(size_t)(k0 + ty + u * 8) * N + (n0 + tx)];
    __syncthreads();
#pragma unroll
    for (int u = 0; u < 4; ++u)
        op[(size_t)(n0 + ty + u * 8) * K + (k0 + tx)] = (bf16_t)t[tx][ty + u * 8];
}

// ---------------------------------------------------------------------------
// LayerNorm, wave-per-row (D=768): 4 rows/block, 1 wave each, no LDS, no
// barriers. Lane holds 3 float4; fused (sum,sumsq) 64-lane butterfly.
// ---------------------------------------------------------------------------
__global__ __launch_bounds__(256) void layernorm_dual(
    const float* __restrict__ X, const float* __restrict__ g,
    const float* __restrict__ b, bf16_t* __restrict__ Yb,
    float* __restrict__ Yf, int D)
{
    const int lane = threadIdx.x & 63;
    const int row  = blockIdx.x * 4 + (threadIdx.x >> 6);

    const float4* xr4 = (const float4*)(X + (size_t)row * D);
    float4 v[3];
#pragma unroll
    for (int u = 0; u < 3; ++u) v[u] = xr4[lane + u * 64];

    float s = 0.f, ss = 0.f;
#pragma unroll
    for (int u = 0; u < 3; ++u) {
        s  += v[u].x + v[u].y + v[u].z + v[u].w;
        ss += v[u].x * v[u].x + v[u].y * v[u].y + v[u].z * v[u].z + v[u].w * v[u].w;
    }
#pragma unroll
    for (int off = 1; off < 64; off <<= 1) {
        s  += __shfl_xor(s,  off);
        ss += __shfl_xor(ss, off);
    }

    const float mean = s / (float)D;
    const float var  = ss / (float)D - mean * mean;
    const float rstd = rsqrtf(var + 1e-6f);

#pragma unroll
    for (int u = 0; u < 3; ++u) {
        const int c4 = lane + u * 64;
        const float4 gv = ((const float4*)g)[c4];
        const float4 bv = ((const float4*)b)[c4];
        const float y0 = (v[u].x - mean) * rstd * gv.x + bv.x;
        const float y1 = (v[u].y - mean) * rstd * gv.y + bv.y;
        const float y2 = (v[u].z - mean) * rstd * gv.z + bv.z;
        const float y3 = (v[u].w - mean) * rstd * gv.w + bv.w;
        bf16x4 yb;
        yb[0] = (bf16_t)y0; yb[1] = (bf16_t)y1; yb[2] = (bf16_t)y2; yb[3] = (bf16_t)y3;
        *(bf16x4*)&Yb[(size_t)row * D + c4 * 4] = yb;
        if (Yf)
            ((float4*)(Yf + (size_t)row * D))[c4] = make_float4(y0, y1, y2, y3);
    }
}

// ---------------------------------------------------------------------------
// Fused flash attention (causal, hd=64, S=512), 64-row q-tiles.
// Grid: (S/64=8, B*H=48)=384 blocks; 4 waves x 16 q-rows each.
// ---------------------------------------------------------------------------
__global__ __launch_bounds__(256) void flash_attn(
    const bf16_t* __restrict__ qkv, bf16_t* __restrict__ o)
{
    constexpr int S = 512, TD = 2304, D = 768, H = 12;
    const int qt = blockIdx.x;          // 0..7
    const int z  = blockIdx.y;
    const int bb = z / H, hh = z - bb * H;
    const int tid = threadIdx.x, lane = tid & 63, w = tid >> 6;
    const int fr = lane & 15, g = lane >> 4, sub = g * 8;

    __shared__ bf16_t kS[2][4096];
    __shared__ bf16_t vS[2][4096];
    __shared__ bf16_t pS[4][16 * 72];

    bf16x8 qf[2];
    const bf16_t* qbase = qkv + (size_t)(bb * S + qt * 64 + w * 16) * TD + hh * 64;
#pragma unroll
    for (int ks = 0; ks < 2; ++ks) {
        bf16x8 v = *(const bf16x8*)&qbase[(size_t)fr * TD + ks * 32 + sub];
#pragma unroll
        for (int j = 0; j < 8; ++j) v[j] = v[j] * (bf16_t)0.125f;
        qf[ks] = v;
    }

    f32x4 oacc[4];
    float mrun[4], lrun[4];
#pragma unroll
    for (int r = 0; r < 4; ++r) { mrun[r] = -3.0e38f; lrun[r] = 0.0f; }
#pragma unroll
    for (int n = 0; n < 4; ++n) oacc[n] = (f32x4){0.f, 0.f, 0.f, 0.f};

    int qr[4];
#pragma unroll
    for (int r = 0; r < 4; ++r) qr[r] = qt * 64 + w * 16 + g * 4 + r;

    const int srow8  = lane >> 3;
    const int schunk = (lane & 7) ^ (srow8 & 7);

    const bf16_t* kGbase = qkv + (size_t)(bb * S) * TD + D + hh * 64;
    const bf16_t* vGbase = qkv + (size_t)(bb * S) * TD + 2 * D + hh * 64;
    const int nkv = qt + 1;

    bf16x8 vreg[2];

#define STAGE_ISSUE(buf, t)                                                     \
    {                                                                           \
        _Pragma("unroll")                                                       \
        for (int it = 0; it < 2; ++it) {                                        \
            const int row = it * 32 + w * 8 + srow8;                            \
            gload16(kGbase + (size_t)((t) * 64 + row) * TD + schunk * 8,        \
                    &kS[buf][it * 2048 + w * 512]);                             \
        }                                                                       \
        _Pragma("unroll")                                                       \
        for (int it = 0; it < 2; ++it) {                                        \
            const int dch = w * 2 + it;                                         \
            vreg[it] = *(const bf16x8*)&vGbase[(size_t)((t) * 64 + lane) * TD + dch * 8]; \
        }                                                                       \
    }
#define STAGE_WRITE(buf)                                                        \
    {                                                                           \
        _Pragma("unroll")                                                       \
        for (int it = 0; it < 2; ++it) {                                        \
            const int dch = w * 2 + it;                                         \
            _Pragma("unroll")                                                   \
            for (int j = 0; j < 8; ++j) {                                       \
                const int d = dch * 8 + j;                                      \
                vS[buf][d * 64 + (((lane >> 3) ^ j) << 3) + (lane & 7)] = vreg[it][j]; \
            }                                                                   \
        }                                                                       \
    }

    STAGE_ISSUE(0, 0);
    STAGE_WRITE(0);
    __syncthreads();

    int cur = 0;
    for (int t = 0; t < nkv; ++t) {
        if (t + 1 < nkv) STAGE_ISSUE(cur ^ 1, t + 1);

        f32x4 sacc[4];
#pragma unroll
        for (int n = 0; n < 4; ++n) sacc[n] = (f32x4){0.f, 0.f, 0.f, 0.f};
#pragma unroll
        for (int ks = 0; ks < 2; ++ks) {
            bf16x8 bK[4];
#pragma unroll
            for (int n = 0; n < 4; ++n) {
                const int rw = n * 16 + fr;
                const int c  = ks * 4 + g;
                bK[n] = *(const bf16x8*)&kS[cur][rw * 64 + ((c ^ (rw & 7)) << 3)];
            }
#pragma unroll
            for (int n = 0; n < 4; ++n)
                sacc[n] = __builtin_amdgcn_mfma_f32_16x16x32_bf16(
                    qf[ks], bK[n], sacc[n], 0, 0, 0);
        }

        if (t == qt) {
#pragma unroll
            for (int n = 0; n < 4; ++n) {
                const int key = t * 64 + n * 16 + fr;
#pragma unroll
                for (int r = 0; r < 4; ++r)
                    if (key > qr[r]) sacc[n][r] = -3.0e38f;
            }
        }

        float sf[4], rs[4];
#pragma unroll
        for (int r = 0; r < 4; ++r) {
            float v = fmaxf(fmaxf(sacc[0][r], sacc[1][r]),
                            fmaxf(sacc[2][r], sacc[3][r]));
#pragma unroll
            for (int off = 1; off < 16; off <<= 1)
                v = fmaxf(v, __shfl_xor(v, off));
            const float mn = fmaxf(mrun[r], v);
            sf[r] = __expf(mrun[r] - mn);
            mrun[r] = mn;
            lrun[r] *= sf[r];
        }
#pragma unroll
        for (int n = 0; n < 4; ++n)
#pragma unroll
            for (int r = 0; r < 4; ++r)
                oacc[n][r] *= sf[r];
#pragma unroll
        for (int r = 0; r < 4; ++r) rs[r] = 0.0f;
#pragma unroll
        for (int n = 0; n < 4; ++n)
#pragma unroll
            for (int r = 0; r < 4; ++r) {
                const float p = __expf(sacc[n][r] - mrun[r]);
                sacc[n][r] = p;
                rs[r] += p;
            }
#pragma unroll
        for (int r = 0; r < 4; ++r) {
            float v = rs[r];
#pragma unroll
            for (int off = 1; off < 16; off <<= 1) v += __shfl_xor(v, off);
            lrun[r] += v;
        }

        bf16_t* pw = pS[w];
#pragma unroll
        for (int n = 0; n < 4; ++n)
#pragma unroll
            for (int r = 0; r < 4; ++r)
                pw[(g * 4 + r) * 72 + n * 16 + fr] = (bf16_t)sacc[n][r];

#pragma unroll
        for (int ks = 0; ks < 2; ++ks) {
            bf16x8 pa, vb[4];
            pa = *(const bf16x8*)&pw[fr * 72 + ks * 32 + sub];
#pragma unroll
            for (int n = 0; n < 4; ++n) {
                const int rw = n * 16 + fr;
                const int c  = ks * 4 + g;
                vb[n] = *(const bf16x8*)&vS[cur][rw * 64 + ((c ^ (rw & 7)) << 3)];
            }
#pragma unroll
            for (int n = 0; n < 4; ++n)
                oacc[n] = __builtin_amdgcn_mfma_f32_16x16x32_bf16(
                    pa, vb[n], oacc[n], 0, 0, 0);
        }

        if (t + 1 < nkv) STAGE_WRITE(cur ^ 1);
        __syncthreads();
        cur ^= 1;
    }
#undef STAGE_ISSUE
#undef STAGE_WRITE

    bf16_t* obase = o + (size_t)(bb * S + qt * 64 + w * 16) * D + hh * 64;
#pragma unroll
    for (int r = 0; r < 4; ++r) {
        const float inv = 1.0f / lrun[r];
#pragma unroll
        for (int n = 0; n < 4; ++n)
            obase[(size_t)(g * 4 + r) * D + n * 16 + fr] =
                (bf16_t)(oacc[n][r] * inv);
    }
}

// ---------------------------------------------------------------------------
// Vocab softmax: bf16 logits (stride Vp) -> f32 probs (stride V).
// Pass 1: single vectorized online (max,sum) read. Pass 2: write probs.
// ---------------------------------------------------------------------------
__global__ __launch_bounds__(256) void softmax_vocab(
    const bf16_t* __restrict__ logits, float* __restrict__ probs, int V, int Vp)
{
    const int tid = threadIdx.x;
    const bf16_t* lr = logits + (size_t)blockIdx.x * Vp;
    float* pr = probs + (size_t)blockIdx.x * V;
    const int n8 = V >> 3;

    float m = -3.0e38f, s = 0.0f;
    for (int c8 = tid; c8 < n8; c8 += 256) {
        const bf16x8 v = *(const bf16x8*)(lr + (size_t)c8 * 8);
        float f[8], lm = -3.0e38f;
#pragma unroll
        for (int j = 0; j < 8; ++j) { f[j] = (float)v[j]; lm = fmaxf(lm, f[j]); }
        if (lm > m) { s *= __expf(m - lm); m = lm; }
#pragma unroll
        for (int j = 0; j < 8; ++j) s += __expf(f[j] - m);
    }
    for (int c = n8 * 8 + tid; c < V; c += 256) {
        const float f = (float)lr[c];
        if (f > m) { s *= __expf(m - f); m = f; }
        s += __expf(f - m);
    }

    __shared__ float mS[256], sS[256];
    mS[tid] = m; sS[tid] = s;
    __syncthreads();
    for (int off = 128; off > 0; off >>= 1) {
        if (tid < off) {
            const float m1 = mS[tid], m2 = mS[tid + off];
            const float M_ = fmaxf(m1, m2);
            sS[tid] = sS[tid] * __expf(m1 - M_) + sS[tid + off] * __expf(m2 - M_);
            mS[tid] = M_;
        }
        __syncthreads();
    }
    const float M_  = mS[0];
    const float inv = 1.0f / sS[0];

    for (int c8 = tid; c8 < n8; c8 += 256) {
        const bf16x8 v = *(const bf16x8*)(lr + (size_t)c8 * 8);
#pragma unroll
        for (int j = 0; j < 8; ++j)
            pr[(size_t)c8 * 8 + j] = __expf((float)v[j] - M_) * inv;
    }
    for (int c = n8 * 8 + tid; c < V; c += 256)
        pr[c] = __expf((float)lr[c] - M_) * inv;
}

// ---------------------------------------------------------------------------
// bf16 MFMA GEMM body (qkv/fc): 128x64 tile, DB 2-phase, BK=64, 4 waves.
// ---------------------------------------------------------------------------
template<bool ADD, bool GELU_, bool OUTBF>
__device__ __forceinline__ void gemm_body(
    const bf16_t* __restrict__ A, const bf16_t* __restrict__ Bw,
    const float* __restrict__ bias, void* __restrict__ Cv,
    int M, int N, int K, int lda, int ldb, int ldc)
{
    constexpr int BUF = 12288;
    __shared__ bf16_t lds[2 * BUF];

    const int tid  = threadIdx.x;
    const int lane = tid & 63;
    const int w    = tid >> 6;
    const int row0 = blockIdx.x * 128;
    const int col0 = blockIdx.y * 64;

    const int row8 = lane >> 3;
    const int sch  = (lane & 7) ^ row8;
    const int fr   = lane & 15;
    const int g    = lane >> 4;

    const int aRowB = row0 + w * 32;
    const int bRowB = col0 + w * 16;

    f32x4 acc[2][4];
#pragma unroll
    for (int m = 0; m < 2; ++m)
#pragma unroll
        for (int n = 0; n < 4; ++n)
            acc[m][n] = (f32x4){0.f, 0.f, 0.f, 0.f};

    auto STAGE = [&](int buf, int k0) {
        bf16_t* lb = lds + buf * BUF;
#pragma unroll
        for (int it = 0; it < 4; ++it) {
            const int ar = aRowB + it * 8 + row8;
            gload16(A + (size_t)ar * lda + k0 + sch * 8, lb + w * 2048 + it * 512);
        }
#pragma unroll
        for (int it = 0; it < 2; ++it) {
            int br = bRowB + it * 8 + row8;
            if (br >= N) br = 0;
            gload16(Bw + (size_t)br * ldb + k0 + sch * 8,
                    lb + 8192 + w * 1024 + it * 512);
        }
    };

    auto COMPUTE = [&](int buf) {
        bf16_t* lb = lds + buf * BUF;
#pragma unroll
        for (int ks = 0; ks < 2; ++ks) {
            bf16x8 af[2], bfr[4];
            const int cs = ks * 4 + g;
#pragma unroll
            for (int m = 0; m < 2; ++m) {
                const int row = w * 32 + m * 16 + fr;
                af[m] = *(const bf16x8*)&lb[row * 64 + ((cs ^ (fr & 7)) << 3)];
            }
#pragma unroll
            for (int n = 0; n < 4; ++n) {
                const int row = n * 16 + fr;
                bfr[n] = *(const bf16x8*)&lb[8192 + row * 64 + ((cs ^ (fr & 7)) << 3)];
            }
#pragma unroll
            for (int m = 0; m < 2; ++m)
#pragma unroll
                for (int n = 0; n < 4; ++n)
                    acc[m][n] = __builtin_amdgcn_mfma_f32_16x16x32_bf16(
                        af[m], bfr[n], acc[m][n], 0, 0, 0);
        }
    };

    const int nt = K >> 6;
    STAGE(0, 0);
    drain_and_barrier();
    int cur = 0;
    for (int t = 0; t < nt; ++t) {
        if (t + 1 < nt) STAGE(cur ^ 1, (t + 1) << 6);
        COMPUTE(cur);
        drain_and_barrier();
        cur ^= 1;
    }

    const int rBase = row0 + w * 32 + g * 4;
    const int cBase = col0 + fr;
    float bv[4];
#pragma unroll
    for (int n = 0; n < 4; ++n) {
        const int c = cBase + n * 16;
        bv[n] = (bias && c < N) ? bias[c] : 0.0f;
    }
#pragma unroll
    for (int m = 0; m < 2; ++m) {
#pragma unroll
        for (int r = 0; r < 4; ++r) {
            const int rr = rBase + m * 16 + r;
#pragma unroll
            for (int n = 0; n < 4; ++n) {
                const int c = cBase + n * 16;
                if (c >= N) continue;
                float v = acc[m][n][r] + bv[n];
                if (GELU_) v = 0.5f * v * (1.0f + erff(v * 0.70710678118654752f));
                if (OUTBF) {
                    ((bf16_t*)Cv)[(size_t)rr * ldc + c] = (bf16_t)v;
                } else {
                    float* Cf = (float*)Cv;
                    const size_t idx = (size_t)rr * ldc + c;
                    if (ADD) v += Cf[idx];
                    Cf[idx] = v;
                }
            }
        }
    }
}

__global__ __launch_bounds__(256) void k_gemm_qkv(
    const bf16_t* A, const bf16_t* B, const float* bias, void* C,
    int M, int N, int K, int lda, int ldb, int ldc)
{ gemm_body<false, false, true>(A, B, bias, C, M, N, K, lda, ldb, ldc); }

__global__ __launch_bounds__(256) void k_gemm_fc(
    const bf16_t* A, const bf16_t* B, const float* bias, void* C,
    int M, int N, int K, int lda, int ldb, int ldc)
{ gemm_body<false, true, true>(A, B, bias, C, M, N, K, lda, ldb, ldc); }

// ---------------------------------------------------------------------------
// Small GEMM (oproj/proj): 64x64 tile, DB 2-phase, BK=64, ~5 blocks/CU.
// ---------------------------------------------------------------------------
__global__ __launch_bounds__(256) void k_gemm_small(
    const bf16_t* __restrict__ A, const bf16_t* __restrict__ Bw,
    const float* __restrict__ bias, float* __restrict__ C,
    int M, int N, int K, int lda, int ldb, int ldc)
{
    constexpr int BUF = 8192;               // A[64][64] @0, B[64][64] @4096
    __shared__ bf16_t lds[2 * BUF];

    const int tid  = threadIdx.x;
    const int lane = tid & 63;
    const int w    = tid >> 6;
    const int row0 = blockIdx.x * 64;
    const int col0 = blockIdx.y * 64;

    const int row8 = lane >> 3;
    const int sch  = (lane & 7) ^ row8;
    const int fr   = lane & 15;
    const int g    = lane >> 4;

    f32x4 acc[4];
#pragma unroll
    for (int m = 0; m < 4; ++m) acc[m] = (f32x4){0.f, 0.f, 0.f, 0.f};

    auto STAGE = [&](int buf, int k0) {
        bf16_t* lb = lds + buf * BUF;
#pragma unroll
        for (int it = 0; it < 2; ++it) {
            const int ar = row0 + it * 32 + w * 8 + row8;
            gload16(A + (size_t)ar * lda + k0 + sch * 8,
                    lb + (it * 32 + w * 8) * 64);
            const int br = col0 + it * 32 + w * 8 + row8;
            gload16(Bw + (size_t)br * ldb + k0 + sch * 8,
                    lb + 4096 + (it * 32 + w * 8) * 64);
        }
    };

    auto COMPUTE = [&](int buf) {
        bf16_t* lb = lds + buf * BUF;
#pragma unroll
        for (int ks = 0; ks < 2; ++ks) {
            const int cs = ks * 4 + g;
            const int bRow = w * 16 + fr;
            bf16x8 bfr = *(const bf16x8*)&lb[4096 + bRow * 64 + ((cs ^ (fr & 7)) << 3)];
#pragma unroll
            for (int m = 0; m < 4; ++m) {
                const int row = m * 16 + fr;
                bf16x8 af = *(const bf16x8*)&lb[row * 64 + ((cs ^ (fr & 7)) << 3)];
                acc[m] = __builtin_amdgcn_mfma_f32_16x16x32_bf16(
                    af, bfr, acc[m], 0, 0, 0);
            }
        }
    };

    const int nt = K >> 6;
    STAGE(0, 0);
    drain_and_barrier();
    int cur = 0;
    for (int t = 0; t < nt; ++t) {
        if (t + 1 < nt) STAGE(cur ^ 1, (t + 1) << 6);
        COMPUTE(cur);
        drain_and_barrier();
        cur ^= 1;
    }

    const int c = col0 + w * 16 + fr;
    const float bv = bias ? bias[c] : 0.0f;
#pragma unroll
    for (int m = 0; m < 4; ++m) {
#pragma unroll
        for (int r = 0; r < 4; ++r) {
            const int rr = row0 + m * 16 + g * 4 + r;
            const size_t idx = (size_t)rr * ldc + c;
            C[idx] += acc[m][r] + bv;
        }
    }
}

// ---------------------------------------------------------------------------
// LM head GEMM: 256x128 tile, BK=64, single-buffer 48KB LDS, 8 waves (4x2).
// y-panel bijective XCD swizzle kept.
// ---------------------------------------------------------------------------
__global__ __launch_bounds__(512) void k_gemm_head(
    const bf16_t* __restrict__ A, const bf16_t* __restrict__ Bw,
    bf16_t* __restrict__ C, int M, int N, int K, int lda, int ldb, int ldc)
{
    __shared__ bf16_t lds[24576];           // A[256][64] @0, B[128][64] @16384

    const int nwg = gridDim.x * gridDim.y;
    int flat = blockIdx.y * gridDim.x + blockIdx.x;
    {
        const int xcd = flat & 7, pos = flat >> 3;
        flat = xcd * (nwg >> 3) + pos;
    }
    const int bx = flat % gridDim.x;
    const int by = flat / gridDim.x;

    const int tid  = threadIdx.x;
    const int lane = tid & 63;
    const int w    = tid >> 6;              // 0..7
    const int wr   = w >> 1, wc = w & 1;    // 4 x 2 wave grid
    const int row0 = bx * 256;
    const int col0 = by * 128;

    const int row8 = lane >> 3;
    const int sch  = (lane & 7) ^ row8;
    const int fr   = lane & 15;
    const int g    = lane >> 4;

    f32x4 acc[4][4];
#pragma unroll
    for (int m = 0; m < 4; ++m)
#pragma unroll
        for (int n = 0; n < 4; ++n)
            acc[m][n] = (f32x4){0.f, 0.f, 0.f, 0.f};

    for (int k0 = 0; k0 < K; k0 += 64) {
#pragma unroll
        for (int it = 0; it < 4; ++it) {
            const int ar = row0 + w * 32 + it * 8 + row8;
            gload16(A + (size_t)ar * lda + k0 + sch * 8,
                    lds + (w * 32 + it * 8) * 64);
        }
#pragma unroll
        for (int it = 0; it < 2; ++it) {
            int br = col0 + w * 16 + it * 8 + row8;
            if (br >= N) br = 0;
            gload16(Bw + (size_t)br * ldb + k0 + sch * 8,
                    lds + 16384 + (w * 16 + it * 8) * 64);
        }
        __syncthreads();

#pragma unroll
        for (int ks = 0; ks < 2; ++ks) {
            bf16x8 af[4], bfr[4];
            const int cs = ks * 4 + g;
#pragma unroll
            for (int m = 0; m < 4; ++m) {
                const int row = wr * 64 + m * 16 + fr;
                af[m] = *(const bf16x8*)&lds[row * 64 + ((cs ^ (fr & 7)) << 3)];
            }
#pragma unroll
            for (int n = 0; n < 4; ++n) {
                const int row = wc * 64 + n * 16 + fr;
                bfr[n] = *(const bf16x8*)&lds[16384 + row * 64 + ((cs ^ (fr & 7)) << 3)];
            }
#pragma unroll
            for (int m = 0; m < 4; ++m)
#pragma unroll
                for (int n = 0; n < 4; ++n)
                    acc[m][n] = __builtin_amdgcn_mfma_f32_16x16x32_bf16(
                        af[m], bfr[n], acc[m][n], 0, 0, 0);
        }
        __syncthreads();
    }

    const int rBase = row0 + wr * 64 + g * 4;
    const int cBase = col0 + wc * 64 + fr;
#pragma unroll
    for (int n = 0; n < 4; ++n) {
        const int c = cBase + n * 16;
        if (c >= N) continue;
#pragma unroll
        for (int m = 0; m < 4; ++m)
#pragma unroll
            for (int r = 0; r < 4; ++r)
                C[(size_t)(rBase + m * 16 + r) * ldc + c] = (bf16_t)acc[m][n][r];
    }
}

// ---------------------------------------------------------------------------
// Launcher
// ---------------------------------------------------------------------------
extern "C" void kernel_launch(void* const* d_in, const int* in_sizes, int n_in,
                              void* d_out, int out_size, void* d_ws, size_t ws_size,
                              hipStream_t stream)
{
    constexpr int B = 4, S = 512, D = 768, L = 12, V = 50257, H = 12, F = 3072;
    constexpr int M  = B * S;     // 2048
    constexpr int TD = 3 * D;     // 2304
    constexpr int BH = B * H;     // 48
    constexpr int Vp = 50264;     // V padded to multiple of 8
    constexpr int NP = (V + 127) / 128;   // 393 column panels

    const int*   x    = (const int*)  d_in[0];
    const float* emb  = (const float*)d_in[1];
    const float* pos  = (const float*)d_in[2];
    const float* ln1g = (const float*)d_in[3];
    const float* ln1b = (const float*)d_in[4];
    const float* wqkv = (const float*)d_in[5];
    const float* bqkv = (const float*)d_in[6];
    const float* wo   = (const float*)d_in[7];
    const float* bo   = (const float*)d_in[8];
    const float* ln2g = (const float*)d_in[9];
    const float* ln2b = (const float*)d_in[10];
    const float* wfc  = (const float*)d_in[11];
    const float* bfc  = (const float*)d_in[12];
    const float* wpr  = (const float*)d_in[13];
    const float* bpr  = (const float*)d_in[14];
    const float* lnfg = (const float*)d_in[15];
    const float* lnfb = (const float*)d_in[16];

    float* probs  = (float*)d_out;                    // [M, V]
    float* hidden = probs + (size_t)M * V;            // [M, D]

    // ---- workspace layout (bump allocator, 256B aligned) ------------------
    char* wsb = (char*)d_ws;
    size_t off = 0;
    auto alloc = [&](size_t bytes) -> char* {
        char* p = wsb + off;
        off += (bytes + 255) & ~(size_t)255;
        return p;
    };
    // live-at-head buffers FIRST (never aliased by logits)
    bf16_t* hid_bf = (bf16_t*)alloc((size_t)M * D * 2);
    bf16_t* embB   = (bf16_t*)alloc((size_t)V * D * 2);
    // trunk region (dead at head time) — logits aliases it
    const size_t trunk_start = off;
    float*  h      = (float*) alloc((size_t)M * D * 4);
    bf16_t* qkv_bf = (bf16_t*)alloc((size_t)M * TD * 2);
    bf16_t* xn_bf  = (bf16_t*)alloc((size_t)M * D * 2);
    bf16_t* o_bf   = (bf16_t*)alloc((size_t)M * D * 2);
    bf16_t* mid_bf = (bf16_t*)alloc((size_t)M * F * 2);
    bf16_t* wqkvT  = (bf16_t*)alloc((size_t)L * D * TD * 2);
    bf16_t* woT    = (bf16_t*)alloc((size_t)L * D * D * 2);
    bf16_t* wfcT   = (bf16_t*)alloc((size_t)L * D * F * 2);
    bf16_t* wprT   = (bf16_t*)alloc((size_t)L * F * D * 2);
    const size_t logits_bytes = (size_t)M * Vp * 2;
    if (off < trunk_start + logits_bytes) off = trunk_start + logits_bytes;
    bf16_t* logits = (bf16_t*)(wsb + trunk_start);

    // ---- weight prep ------------------------------------------------------
    convert_bf16<<<2048, 256, 0, stream>>>(emb, embB, (V * D) / 4);
    transpose_to_bf16<<<dim3(TD / 32, D / 32, L), dim3(32, 8), 0, stream>>>(wqkv, wqkvT, D, TD);
    transpose_to_bf16<<<dim3(D / 32,  D / 32, L), dim3(32, 8), 0, stream>>>(wo,   woT,   D, D);
    transpose_to_bf16<<<dim3(F / 32,  D / 32, L), dim3(32, 8), 0, stream>>>(wfc,  wfcT,  D, F);
    transpose_to_bf16<<<dim3(D / 32,  F / 32, L), dim3(32, 8), 0, stream>>>(wpr,  wprT,  F, D);

    // ---- embedding
    embed_kernel<<<dim3((M * D + 255) / 256), 256, 0, stream>>>(x, emb, pos, h, S, D, M * D);

    for (int i = 0; i < L; ++i) {
        layernorm_dual<<<M / 4, 256, 0, stream>>>(h, ln1g + (size_t)i * D, ln1b + (size_t)i * D,
                                                  xn_bf, nullptr, D);

        k_gemm_qkv<<<dim3(M / 128, TD / 64), 256, 0, stream>>>(
            xn_bf, wqkvT + (size_t)i * D * TD, bqkv + (size_t)i * TD, qkv_bf,
            M, TD, D, D, D, TD);

        flash_attn<<<dim3(S / 64, BH), 256, 0, stream>>>(qkv_bf, o_bf);

        k_gemm_small<<<dim3(M / 64, D / 64), 256, 0, stream>>>(
            o_bf, woT + (size_t)i * D * D, bo + (size_t)i * D, h,
            M, D, D, D, D, D);

        layernorm_dual<<<M / 4, 256, 0, stream>>>(h, ln2g + (size_t)i * D, ln2b + (size_t)i * D,
                                                  xn_bf, nullptr, D);

        k_gemm_fc<<<dim3(M / 128, F / 64), 256, 0, stream>>>(
            xn_bf, wfcT + (size_t)i * D * F, bfc + (size_t)i * F, mid_bf,
            M, F, D, D, D, F);

        k_gemm_small<<<dim3(M / 64, D / 64), 256, 0, stream>>>(
            mid_bf, wprT + (size_t)i * F * D, bpr + (size_t)i * D, h,
            M, D, F, F, F, D);
    }

    layernorm_dual<<<M / 4, 256, 0, stream>>>(h, lnfg, lnfb, hid_bf, hidden, D);

    k_gemm_head<<<dim3(M / 256, NP), 512, 0, stream>>>(
        hid_bf, embB, logits,
        M, V, D, D, D, Vp);

    softmax_vocab<<<M, 256, 0, stream>>>(logits, probs, V, Vp);
}

// Round 20
// 1989.192 us; speedup vs baseline: 1.0050x; 1.0050x over previous
//
#include <hip/hip_runtime.h>
#include <hip/hip_bf16.h>

typedef __bf16 bf16_t;
typedef bf16_t bf16x8 __attribute__((ext_vector_type(8)));
typedef bf16_t bf16x4 __attribute__((ext_vector_type(4)));
typedef float  f32x4  __attribute__((ext_vector_type(4)));

// ---------------------------------------------------------------------------
// global -> LDS async copy, 16B per lane. lds base must be wave-uniform.
// ---------------------------------------------------------------------------
__device__ __forceinline__ void gload16(const void* g, void* l) {
    __builtin_amdgcn_global_load_lds(
        (const __attribute__((address_space(1))) unsigned int*)g,
        (__attribute__((address_space(3))) unsigned int*)l, 16, 0, 0);
}

__device__ __forceinline__ void drain_and_barrier() {
    __builtin_amdgcn_sched_barrier(0);
    asm volatile("s_waitcnt vmcnt(0)" ::: "memory");
    __builtin_amdgcn_s_barrier();
    __builtin_amdgcn_sched_barrier(0);
}

// ---------------------------------------------------------------------------
// Embedding: h[b,s,:] = emb[x[b,s],:] + posemb[s,:]
// ---------------------------------------------------------------------------
__global__ void embed_kernel(const int* __restrict__ x,
                             const float* __restrict__ emb,
                             const float* __restrict__ pos,
                             float* __restrict__ h,
                             int S, int D, int total)
{
    int i = blockIdx.x * blockDim.x + threadIdx.x;
    if (i >= total) return;
    int d  = i % D;
    int bs = i / D;
    int s  = bs % S;
    h[i] = emb[(long long)x[bs] * D + d] + pos[(long long)s * D + d];
}

// ---------------------------------------------------------------------------
// elementwise f32 -> bf16 (vectorized by 4)
// ---------------------------------------------------------------------------
__global__ void convert_bf16(const float* __restrict__ in, bf16_t* __restrict__ out, int n4)
{
    int i = blockIdx.x * blockDim.x + threadIdx.x;
    for (; i < n4; i += gridDim.x * blockDim.x) {
        float4 v = ((const float4*)in)[i];
        bf16_t* o = out + (size_t)i * 4;
        o[0] = (bf16_t)v.x; o[1] = (bf16_t)v.y; o[2] = (bf16_t)v.z; o[3] = (bf16_t)v.w;
    }
}

// ---------------------------------------------------------------------------
// Batched transpose + bf16 convert: out[z][n][k] = (bf16) in[z][k][n]
// ---------------------------------------------------------------------------
__global__ __launch_bounds__(256) void transpose_to_bf16(
    const float* __restrict__ in, bf16_t* __restrict__ out, int K, int N)
{
    const float* ip = in  + (size_t)blockIdx.z * K * N;
    bf16_t*      op = out + (size_t)blockIdx.z * K * N;
    __shared__ float t[32][33];
    const int n0 = blockIdx.x * 32, k0 = blockIdx.y * 32;
    const int tx = threadIdx.x, ty = threadIdx.y;
#pragma unroll
    for (int u = 0; u < 4; ++u)
        t[ty + u * 8][tx] = ip[(size_t)(k0 + ty + u * 8) * N + (n0 + tx)];
    __syncthreads();
#pragma unroll
    for (int u = 0; u < 4; ++u)
        op[(size_t)(n0 + ty + u * 8) * K + (k0 + tx)] = (bf16_t)t[tx][ty + u * 8];
}

// ---------------------------------------------------------------------------
// LayerNorm rows of D=768 (single-pass, vectorized; round-18 measured-best).
// 192 active threads x float4; fused (sum, sumsq) wave-shuffle reduction,
// one barrier; bf16x4 + float4 stores.
// ---------------------------------------------------------------------------
__global__ __launch_bounds__(256) void layernorm_dual(
    const float* __restrict__ X, const float* __restrict__ g,
    const float* __restrict__ b, bf16_t* __restrict__ Yb,
    float* __restrict__ Yf, int D)
{
    const int row = blockIdx.x;
    const int tid = threadIdx.x;
    const int lane = tid & 63, w = tid >> 6;
    const int nf4 = D >> 2;                 // 192

    const float4* xr4 = (const float4*)(X + (size_t)row * D);
    float4 v = (tid < nf4) ? xr4[tid] : make_float4(0.f, 0.f, 0.f, 0.f);

    float s  = v.x + v.y + v.z + v.w;
    float ss = v.x * v.x + v.y * v.y + v.z * v.z + v.w * v.w;
#pragma unroll
    for (int off = 1; off < 64; off <<= 1) {
        s  += __shfl_xor(s,  off);
        ss += __shfl_xor(ss, off);
    }

    __shared__ float sm[8];
    if (lane == 0) { sm[w] = s; sm[4 + w] = ss; }
    __syncthreads();
    s  = sm[0] + sm[1] + sm[2] + sm[3];
    ss = sm[4] + sm[5] + sm[6] + sm[7];

    const float mean = s / (float)D;
    const float var  = ss / (float)D - mean * mean;
    const float rstd = rsqrtf(var + 1e-6f);

    if (tid < nf4) {
        const float4 gv = ((const float4*)g)[tid];
        const float4 bvv = ((const float4*)b)[tid];
        const float y0 = (v.x - mean) * rstd * gv.x + bvv.x;
        const float y1 = (v.y - mean) * rstd * gv.y + bvv.y;
        const float y2 = (v.z - mean) * rstd * gv.z + bvv.z;
        const float y3 = (v.w - mean) * rstd * gv.w + bvv.w;
        bf16x4 yb;
        yb[0] = (bf16_t)y0; yb[1] = (bf16_t)y1; yb[2] = (bf16_t)y2; yb[3] = (bf16_t)y3;
        *(bf16x4*)&Yb[(size_t)row * D + tid * 4] = yb;
        if (Yf)
            ((float4*)(Yf + (size_t)row * D))[tid] = make_float4(y0, y1, y2, y3);
    }
}

// ---------------------------------------------------------------------------
// Fused flash attention (causal, hd=64, S=512), 64-row q-tiles.
// Grid: (S/64=8, B*H=48)=384 blocks; 4 waves x 16 q-rows each.
// ---------------------------------------------------------------------------
__global__ __launch_bounds__(256) void flash_attn(
    const bf16_t* __restrict__ qkv, bf16_t* __restrict__ o)
{
    constexpr int S = 512, TD = 2304, D = 768, H = 12;
    const int qt = blockIdx.x;          // 0..7
    const int z  = blockIdx.y;
    const int bb = z / H, hh = z - bb * H;
    const int tid = threadIdx.x, lane = tid & 63, w = tid >> 6;
    const int fr = lane & 15, g = lane >> 4, sub = g * 8;

    __shared__ bf16_t kS[2][4096];
    __shared__ bf16_t vS[2][4096];
    __shared__ bf16_t pS[4][16 * 72];

    bf16x8 qf[2];
    const bf16_t* qbase = qkv + (size_t)(bb * S + qt * 64 + w * 16) * TD + hh * 64;
#pragma unroll
    for (int ks = 0; ks < 2; ++ks) {
        bf16x8 v = *(const bf16x8*)&qbase[(size_t)fr * TD + ks * 32 + sub];
#pragma unroll
        for (int j = 0; j < 8; ++j) v[j] = v[j] * (bf16_t)0.125f;
        qf[ks] = v;
    }

    f32x4 oacc[4];
    float mrun[4], lrun[4];
#pragma unroll
    for (int r = 0; r < 4; ++r) { mrun[r] = -3.0e38f; lrun[r] = 0.0f; }
#pragma unroll
    for (int n = 0; n < 4; ++n) oacc[n] = (f32x4){0.f, 0.f, 0.f, 0.f};

    int qr[4];
#pragma unroll
    for (int r = 0; r < 4; ++r) qr[r] = qt * 64 + w * 16 + g * 4 + r;

    const int srow8  = lane >> 3;
    const int schunk = (lane & 7) ^ (srow8 & 7);

    const bf16_t* kGbase = qkv + (size_t)(bb * S) * TD + D + hh * 64;
    const bf16_t* vGbase = qkv + (size_t)(bb * S) * TD + 2 * D + hh * 64;
    const int nkv = qt + 1;

    bf16x8 vreg[2];

#define STAGE_ISSUE(buf, t)                                                     \
    {                                                                           \
        _Pragma("unroll")                                                       \
        for (int it = 0; it < 2; ++it) {                                        \
            const int row = it * 32 + w * 8 + srow8;                            \
            gload16(kGbase + (size_t)((t) * 64 + row) * TD + schunk * 8,        \
                    &kS[buf][it * 2048 + w * 512]);                             \
        }                                                                       \
        _Pragma("unroll")                                                       \
        for (int it = 0; it < 2; ++it) {                                        \
            const int dch = w * 2 + it;                                         \
            vreg[it] = *(const bf16x8*)&vGbase[(size_t)((t) * 64 + lane) * TD + dch * 8]; \
        }                                                                       \
    }
#define STAGE_WRITE(buf)                                                        \
    {                                                                           \
        _Pragma("unroll")                                                       \
        for (int it = 0; it < 2; ++it) {                                        \
            const int dch = w * 2 + it;                                         \
            _Pragma("unroll")                                                   \
            for (int j = 0; j < 8; ++j) {                                       \
                const int d = dch * 8 + j;                                      \
                vS[buf][d * 64 + (((lane >> 3) ^ j) << 3) + (lane & 7)] = vreg[it][j]; \
            }                                                                   \
        }                                                                       \
    }

    STAGE_ISSUE(0, 0);
    STAGE_WRITE(0);
    __syncthreads();

    int cur = 0;
    for (int t = 0; t < nkv; ++t) {
        if (t + 1 < nkv) STAGE_ISSUE(cur ^ 1, t + 1);

        f32x4 sacc[4];
#pragma unroll
        for (int n = 0; n < 4; ++n) sacc[n] = (f32x4){0.f, 0.f, 0.f, 0.f};
#pragma unroll
        for (int ks = 0; ks < 2; ++ks) {
            bf16x8 bK[4];
#pragma unroll
            for (int n = 0; n < 4; ++n) {
                const int rw = n * 16 + fr;
                const int c  = ks * 4 + g;
                bK[n] = *(const bf16x8*)&kS[cur][rw * 64 + ((c ^ (rw & 7)) << 3)];
            }
#pragma unroll
            for (int n = 0; n < 4; ++n)
                sacc[n] = __builtin_amdgcn_mfma_f32_16x16x32_bf16(
                    qf[ks], bK[n], sacc[n], 0, 0, 0);
        }

        if (t == qt) {
#pragma unroll
            for (int n = 0; n < 4; ++n) {
                const int key = t * 64 + n * 16 + fr;
#pragma unroll
                for (int r = 0; r < 4; ++r)
                    if (key > qr[r]) sacc[n][r] = -3.0e38f;
            }
        }

        float sf[4], rs[4];
#pragma unroll
        for (int r = 0; r < 4; ++r) {
            float v = fmaxf(fmaxf(sacc[0][r], sacc[1][r]),
                            fmaxf(sacc[2][r], sacc[3][r]));
#pragma unroll
            for (int off = 1; off < 16; off <<= 1)
                v = fmaxf(v, __shfl_xor(v, off));
            const float mn = fmaxf(mrun[r], v);
            sf[r] = __expf(mrun[r] - mn);
            mrun[r] = mn;
            lrun[r] *= sf[r];
        }
#pragma unroll
        for (int n = 0; n < 4; ++n)
#pragma unroll
            for (int r = 0; r < 4; ++r)
                oacc[n][r] *= sf[r];
#pragma unroll
        for (int r = 0; r < 4; ++r) rs[r] = 0.0f;
#pragma unroll
        for (int n = 0; n < 4; ++n)
#pragma unroll
            for (int r = 0; r < 4; ++r) {
                const float p = __expf(sacc[n][r] - mrun[r]);
                sacc[n][r] = p;
                rs[r] += p;
            }
#pragma unroll
        for (int r = 0; r < 4; ++r) {
            float v = rs[r];
#pragma unroll
            for (int off = 1; off < 16; off <<= 1) v += __shfl_xor(v, off);
            lrun[r] += v;
        }

        bf16_t* pw = pS[w];
#pragma unroll
        for (int n = 0; n < 4; ++n)
#pragma unroll
            for (int r = 0; r < 4; ++r)
                pw[(g * 4 + r) * 72 + n * 16 + fr] = (bf16_t)sacc[n][r];

#pragma unroll
        for (int ks = 0; ks < 2; ++ks) {
            bf16x8 pa, vb[4];
            pa = *(const bf16x8*)&pw[fr * 72 + ks * 32 + sub];
#pragma unroll
            for (int n = 0; n < 4; ++n) {
                const int rw = n * 16 + fr;
                const int c  = ks * 4 + g;
                vb[n] = *(const bf16x8*)&vS[cur][rw * 64 + ((c ^ (rw & 7)) << 3)];
            }
#pragma unroll
            for (int n = 0; n < 4; ++n)
                oacc[n] = __builtin_amdgcn_mfma_f32_16x16x32_bf16(
                    pa, vb[n], oacc[n], 0, 0, 0);
        }

        if (t + 1 < nkv) STAGE_WRITE(cur ^ 1);
        __syncthreads();
        cur ^= 1;
    }
#undef STAGE_ISSUE
#undef STAGE_WRITE

    bf16_t* obase = o + (size_t)(bb * S + qt * 64 + w * 16) * D + hh * 64;
#pragma unroll
    for (int r = 0; r < 4; ++r) {
        const float inv = 1.0f / lrun[r];
#pragma unroll
        for (int n = 0; n < 4; ++n)
            obase[(size_t)(g * 4 + r) * D + n * 16 + fr] =
                (bf16_t)(oacc[n][r] * inv);
    }
}

// ---------------------------------------------------------------------------
// Vocab softmax: bf16 logits (stride Vp) -> f32 probs (stride V).
// Pass 1: single vectorized online (max,sum) read. Pass 2: write probs.
// ---------------------------------------------------------------------------
__global__ __launch_bounds__(256) void softmax_vocab(
    const bf16_t* __restrict__ logits, float* __restrict__ probs, int V, int Vp)
{
    const int tid = threadIdx.x;
    const bf16_t* lr = logits + (size_t)blockIdx.x * Vp;
    float* pr = probs + (size_t)blockIdx.x * V;
    const int n8 = V >> 3;

    float m = -3.0e38f, s = 0.0f;
    for (int c8 = tid; c8 < n8; c8 += 256) {
        const bf16x8 v = *(const bf16x8*)(lr + (size_t)c8 * 8);
        float f[8], lm = -3.0e38f;
#pragma unroll
        for (int j = 0; j < 8; ++j) { f[j] = (float)v[j]; lm = fmaxf(lm, f[j]); }
        if (lm > m) { s *= __expf(m - lm); m = lm; }
#pragma unroll
        for (int j = 0; j < 8; ++j) s += __expf(f[j] - m);
    }
    for (int c = n8 * 8 + tid; c < V; c += 256) {
        const float f = (float)lr[c];
        if (f > m) { s *= __expf(m - f); m = f; }
        s += __expf(f - m);
    }

    __shared__ float mS[256], sS[256];
    mS[tid] = m; sS[tid] = s;
    __syncthreads();
    for (int off = 128; off > 0; off >>= 1) {
        if (tid < off) {
            const float m1 = mS[tid], m2 = mS[tid + off];
            const float M_ = fmaxf(m1, m2);
            sS[tid] = sS[tid] * __expf(m1 - M_) + sS[tid + off] * __expf(m2 - M_);
            mS[tid] = M_;
        }
        __syncthreads();
    }
    const float M_  = mS[0];
    const float inv = 1.0f / sS[0];

    for (int c8 = tid; c8 < n8; c8 += 256) {
        const bf16x8 v = *(const bf16x8*)(lr + (size_t)c8 * 8);
#pragma unroll
        for (int j = 0; j < 8; ++j)
            pr[(size_t)c8 * 8 + j] = __expf((float)v[j] - M_) * inv;
    }
    for (int c = n8 * 8 + tid; c < V; c += 256)
        pr[c] = __expf((float)lr[c] - M_) * inv;
}

// ---------------------------------------------------------------------------
// bf16 MFMA GEMM body (qkv/fc): 128x64 tile, DB 2-phase, BK=64, 4 waves.
// ---------------------------------------------------------------------------
template<bool ADD, bool GELU_, bool OUTBF>
__device__ __forceinline__ void gemm_body(
    const bf16_t* __restrict__ A, const bf16_t* __restrict__ Bw,
    const float* __restrict__ bias, void* __restrict__ Cv,
    int M, int N, int K, int lda, int ldb, int ldc)
{
    constexpr int BUF = 12288;
    __shared__ bf16_t lds[2 * BUF];

    const int tid  = threadIdx.x;
    const int lane = tid & 63;
    const int w    = tid >> 6;
    const int row0 = blockIdx.x * 128;
    const int col0 = blockIdx.y * 64;

    const int row8 = lane >> 3;
    const int sch  = (lane & 7) ^ row8;
    const int fr   = lane & 15;
    const int g    = lane >> 4;

    const int aRowB = row0 + w * 32;
    const int bRowB = col0 + w * 16;

    f32x4 acc[2][4];
#pragma unroll
    for (int m = 0; m < 2; ++m)
#pragma unroll
        for (int n = 0; n < 4; ++n)
            acc[m][n] = (f32x4){0.f, 0.f, 0.f, 0.f};

    auto STAGE = [&](int buf, int k0) {
        bf16_t* lb = lds + buf * BUF;
#pragma unroll
        for (int it = 0; it < 4; ++it) {
            const int ar = aRowB + it * 8 + row8;
            gload16(A + (size_t)ar * lda + k0 + sch * 8, lb + w * 2048 + it * 512);
        }
#pragma unroll
        for (int it = 0; it < 2; ++it) {
            int br = bRowB + it * 8 + row8;
            if (br >= N) br = 0;
            gload16(Bw + (size_t)br * ldb + k0 + sch * 8,
                    lb + 8192 + w * 1024 + it * 512);
        }
    };

    auto COMPUTE = [&](int buf) {
        bf16_t* lb = lds + buf * BUF;
#pragma unroll
        for (int ks = 0; ks < 2; ++ks) {
            bf16x8 af[2], bfr[4];
            const int cs = ks * 4 + g;
#pragma unroll
            for (int m = 0; m < 2; ++m) {
                const int row = w * 32 + m * 16 + fr;
                af[m] = *(const bf16x8*)&lb[row * 64 + ((cs ^ (fr & 7)) << 3)];
            }
#pragma unroll
            for (int n = 0; n < 4; ++n) {
                const int row = n * 16 + fr;
                bfr[n] = *(const bf16x8*)&lb[8192 + row * 64 + ((cs ^ (fr & 7)) << 3)];
            }
#pragma unroll
            for (int m = 0; m < 2; ++m)
#pragma unroll
                for (int n = 0; n < 4; ++n)
                    acc[m][n] = __builtin_amdgcn_mfma_f32_16x16x32_bf16(
                        af[m], bfr[n], acc[m][n], 0, 0, 0);
        }
    };

    const int nt = K >> 6;
    STAGE(0, 0);
    drain_and_barrier();
    int cur = 0;
    for (int t = 0; t < nt; ++t) {
        if (t + 1 < nt) STAGE(cur ^ 1, (t + 1) << 6);
        COMPUTE(cur);
        drain_and_barrier();
        cur ^= 1;
    }

    const int rBase = row0 + w * 32 + g * 4;
    const int cBase = col0 + fr;
    float bv[4];
#pragma unroll
    for (int n = 0; n < 4; ++n) {
        const int c = cBase + n * 16;
        bv[n] = (bias && c < N) ? bias[c] : 0.0f;
    }
#pragma unroll
    for (int m = 0; m < 2; ++m) {
#pragma unroll
        for (int r = 0; r < 4; ++r) {
            const int rr = rBase + m * 16 + r;
#pragma unroll
            for (int n = 0; n < 4; ++n) {
                const int c = cBase + n * 16;
                if (c >= N) continue;
                float v = acc[m][n][r] + bv[n];
                if (GELU_) v = 0.5f * v * (1.0f + erff(v * 0.70710678118654752f));
                if (OUTBF) {
                    ((bf16_t*)Cv)[(size_t)rr * ldc + c] = (bf16_t)v;
                } else {
                    float* Cf = (float*)Cv;
                    const size_t idx = (size_t)rr * ldc + c;
                    if (ADD) v += Cf[idx];
                    Cf[idx] = v;
                }
            }
        }
    }
}

__global__ __launch_bounds__(256) void k_gemm_qkv(
    const bf16_t* A, const bf16_t* B, const float* bias, void* C,
    int M, int N, int K, int lda, int ldb, int ldc)
{ gemm_body<false, false, true>(A, B, bias, C, M, N, K, lda, ldb, ldc); }

__global__ __launch_bounds__(256) void k_gemm_fc(
    const bf16_t* A, const bf16_t* B, const float* bias, void* C,
    int M, int N, int K, int lda, int ldb, int ldc)
{ gemm_body<false, true, true>(A, B, bias, C, M, N, K, lda, ldb, ldc); }

// ---------------------------------------------------------------------------
// Small GEMM (oproj/proj): 64x64 tile, DB 2-phase, BK=64, ~5 blocks/CU.
// ---------------------------------------------------------------------------
__global__ __launch_bounds__(256) void k_gemm_small(
    const bf16_t* __restrict__ A, const bf16_t* __restrict__ Bw,
    const float* __restrict__ bias, float* __restrict__ C,
    int M, int N, int K, int lda, int ldb, int ldc)
{
    constexpr int BUF = 8192;               // A[64][64] @0, B[64][64] @4096
    __shared__ bf16_t lds[2 * BUF];

    const int tid  = threadIdx.x;
    const int lane = tid & 63;
    const int w    = tid >> 6;
    const int row0 = blockIdx.x * 64;
    const int col0 = blockIdx.y * 64;

    const int row8 = lane >> 3;
    const int sch  = (lane & 7) ^ row8;
    const int fr   = lane & 15;
    const int g    = lane >> 4;

    f32x4 acc[4];
#pragma unroll
    for (int m = 0; m < 4; ++m) acc[m] = (f32x4){0.f, 0.f, 0.f, 0.f};

    auto STAGE = [&](int buf, int k0) {
        bf16_t* lb = lds + buf * BUF;
#pragma unroll
        for (int it = 0; it < 2; ++it) {
            const int ar = row0 + it * 32 + w * 8 + row8;
            gload16(A + (size_t)ar * lda + k0 + sch * 8,
                    lb + (it * 32 + w * 8) * 64);
            const int br = col0 + it * 32 + w * 8 + row8;
            gload16(Bw + (size_t)br * ldb + k0 + sch * 8,
                    lb + 4096 + (it * 32 + w * 8) * 64);
        }
    };

    auto COMPUTE = [&](int buf) {
        bf16_t* lb = lds + buf * BUF;
#pragma unroll
        for (int ks = 0; ks < 2; ++ks) {
            const int cs = ks * 4 + g;
            const int bRow = w * 16 + fr;
            bf16x8 bfr = *(const bf16x8*)&lb[4096 + bRow * 64 + ((cs ^ (fr & 7)) << 3)];
#pragma unroll
            for (int m = 0; m < 4; ++m) {
                const int row = m * 16 + fr;
                bf16x8 af = *(const bf16x8*)&lb[row * 64 + ((cs ^ (fr & 7)) << 3)];
                acc[m] = __builtin_amdgcn_mfma_f32_16x16x32_bf16(
                    af, bfr, acc[m], 0, 0, 0);
            }
        }
    };

    const int nt = K >> 6;
    STAGE(0, 0);
    drain_and_barrier();
    int cur = 0;
    for (int t = 0; t < nt; ++t) {
        if (t + 1 < nt) STAGE(cur ^ 1, (t + 1) << 6);
        COMPUTE(cur);
        drain_and_barrier();
        cur ^= 1;
    }

    const int c = col0 + w * 16 + fr;
    const float bv = bias ? bias[c] : 0.0f;
#pragma unroll
    for (int m = 0; m < 4; ++m) {
#pragma unroll
        for (int r = 0; r < 4; ++r) {
            const int rr = row0 + m * 16 + g * 4 + r;
            const size_t idx = (size_t)rr * ldc + c;
            C[idx] += acc[m][r] + bv;
        }
    }
}

// ---------------------------------------------------------------------------
// LM head GEMM: 256x128 tile, BK=64, single-buffer 48KB LDS, 8 waves (4x2).
// y-panel bijective XCD swizzle kept.
// ---------------------------------------------------------------------------
__global__ __launch_bounds__(512) void k_gemm_head(
    const bf16_t* __restrict__ A, const bf16_t* __restrict__ Bw,
    bf16_t* __restrict__ C, int M, int N, int K, int lda, int ldb, int ldc)
{
    __shared__ bf16_t lds[24576];           // A[256][64] @0, B[128][64] @16384

    const int nwg = gridDim.x * gridDim.y;
    int flat = blockIdx.y * gridDim.x + blockIdx.x;
    {
        const int xcd = flat & 7, pos = flat >> 3;
        flat = xcd * (nwg >> 3) + pos;
    }
    const int bx = flat % gridDim.x;
    const int by = flat / gridDim.x;

    const int tid  = threadIdx.x;
    const int lane = tid & 63;
    const int w    = tid >> 6;              // 0..7
    const int wr   = w >> 1, wc = w & 1;    // 4 x 2 wave grid
    const int row0 = bx * 256;
    const int col0 = by * 128;

    const int row8 = lane >> 3;
    const int sch  = (lane & 7) ^ row8;
    const int fr   = lane & 15;
    const int g    = lane >> 4;

    f32x4 acc[4][4];
#pragma unroll
    for (int m = 0; m < 4; ++m)
#pragma unroll
        for (int n = 0; n < 4; ++n)
            acc[m][n] = (f32x4){0.f, 0.f, 0.f, 0.f};

    for (int k0 = 0; k0 < K; k0 += 64) {
#pragma unroll
        for (int it = 0; it < 4; ++it) {
            const int ar = row0 + w * 32 + it * 8 + row8;
            gload16(A + (size_t)ar * lda + k0 + sch * 8,
                    lds + (w * 32 + it * 8) * 64);
        }
#pragma unroll
        for (int it = 0; it < 2; ++it) {
            int br = col0 + w * 16 + it * 8 + row8;
            if (br >= N) br = 0;
            gload16(Bw + (size_t)br * ldb + k0 + sch * 8,
                    lds + 16384 + (w * 16 + it * 8) * 64);
        }
        __syncthreads();

#pragma unroll
        for (int ks = 0; ks < 2; ++ks) {
            bf16x8 af[4], bfr[4];
            const int cs = ks * 4 + g;
#pragma unroll
            for (int m = 0; m < 4; ++m) {
                const int row = wr * 64 + m * 16 + fr;
                af[m] = *(const bf16x8*)&lds[row * 64 + ((cs ^ (fr & 7)) << 3)];
            }
#pragma unroll
            for (int n = 0; n < 4; ++n) {
                const int row = wc * 64 + n * 16 + fr;
                bfr[n] = *(const bf16x8*)&lds[16384 + row * 64 + ((cs ^ (fr & 7)) << 3)];
            }
#pragma unroll
            for (int m = 0; m < 4; ++m)
#pragma unroll
                for (int n = 0; n < 4; ++n)
                    acc[m][n] = __builtin_amdgcn_mfma_f32_16x16x32_bf16(
                        af[m], bfr[n], acc[m][n], 0, 0, 0);
        }
        __syncthreads();
    }

    const int rBase = row0 + wr * 64 + g * 4;
    const int cBase = col0 + wc * 64 + fr;
#pragma unroll
    for (int n = 0; n < 4; ++n) {
        const int c = cBase + n * 16;
        if (c >= N) continue;
#pragma unroll
        for (int m = 0; m < 4; ++m)
#pragma unroll
            for (int r = 0; r < 4; ++r)
                C[(size_t)(rBase + m * 16 + r) * ldc + c] = (bf16_t)acc[m][n][r];
    }
}

// ---------------------------------------------------------------------------
// Launcher
// ---------------------------------------------------------------------------
extern "C" void kernel_launch(void* const* d_in, const int* in_sizes, int n_in,
                              void* d_out, int out_size, void* d_ws, size_t ws_size,
                              hipStream_t stream)
{
    constexpr int B = 4, S = 512, D = 768, L = 12, V = 50257, H = 12, F = 3072;
    constexpr int M  = B * S;     // 2048
    constexpr int TD = 3 * D;     // 2304
    constexpr int BH = B * H;     // 48
    constexpr int Vp = 50264;     // V padded to multiple of 8
    constexpr int NP = (V + 127) / 128;   // 393 column panels

    const int*   x    = (const int*)  d_in[0];
    const float* emb  = (const float*)d_in[1];
    const float* pos  = (const float*)d_in[2];
    const float* ln1g = (const float*)d_in[3];
    const float* ln1b = (const float*)d_in[4];
    const float* wqkv = (const float*)d_in[5];
    const float* bqkv = (const float*)d_in[6];
    const float* wo   = (const float*)d_in[7];
    const float* bo   = (const float*)d_in[8];
    const float* ln2g = (const float*)d_in[9];
    const float* ln2b = (const float*)d_in[10];
    const float* wfc  = (const float*)d_in[11];
    const float* bfc  = (const float*)d_in[12];
    const float* wpr  = (const float*)d_in[13];
    const float* bpr  = (const float*)d_in[14];
    const float* lnfg = (const float*)d_in[15];
    const float* lnfb = (const float*)d_in[16];

    float* probs  = (float*)d_out;                    // [M, V]
    float* hidden = probs + (size_t)M * V;            // [M, D]

    // ---- workspace layout (bump allocator, 256B aligned) ------------------
    char* wsb = (char*)d_ws;
    size_t off = 0;
    auto alloc = [&](size_t bytes) -> char* {
        char* p = wsb + off;
        off += (bytes + 255) & ~(size_t)255;
        return p;
    };
    // live-at-head buffers FIRST (never aliased by logits)
    bf16_t* hid_bf = (bf16_t*)alloc((size_t)M * D * 2);
    bf16_t* embB   = (bf16_t*)alloc((size_t)V * D * 2);
    // trunk region (dead at head time) — logits aliases it
    const size_t trunk_start = off;
    float*  h      = (float*) alloc((size_t)M * D * 4);
    bf16_t* qkv_bf = (bf16_t*)alloc((size_t)M * TD * 2);
    bf16_t* xn_bf  = (bf16_t*)alloc((size_t)M * D * 2);
    bf16_t* o_bf   = (bf16_t*)alloc((size_t)M * D * 2);
    bf16_t* mid_bf = (bf16_t*)alloc((size_t)M * F * 2);
    bf16_t* wqkvT  = (bf16_t*)alloc((size_t)L * D * TD * 2);
    bf16_t* woT    = (bf16_t*)alloc((size_t)L * D * D * 2);
    bf16_t* wfcT   = (bf16_t*)alloc((size_t)L * D * F * 2);
    bf16_t* wprT   = (bf16_t*)alloc((size_t)L * F * D * 2);
    const size_t logits_bytes = (size_t)M * Vp * 2;
    if (off < trunk_start + logits_bytes) off = trunk_start + logits_bytes;
    bf16_t* logits = (bf16_t*)(wsb + trunk_start);

    // ---- weight prep ------------------------------------------------------
    convert_bf16<<<2048, 256, 0, stream>>>(emb, embB, (V * D) / 4);
    transpose_to_bf16<<<dim3(TD / 32, D / 32, L), dim3(32, 8), 0, stream>>>(wqkv, wqkvT, D, TD);
    transpose_to_bf16<<<dim3(D / 32,  D / 32, L), dim3(32, 8), 0, stream>>>(wo,   woT,   D, D);
    transpose_to_bf16<<<dim3(F / 32,  D / 32, L), dim3(32, 8), 0, stream>>>(wfc,  wfcT,  D, F);
    transpose_to_bf16<<<dim3(D / 32,  F / 32, L), dim3(32, 8), 0, stream>>>(wpr,  wprT,  F, D);

    // ---- embedding
    embed_kernel<<<dim3((M * D + 255) / 256), 256, 0, stream>>>(x, emb, pos, h, S, D, M * D);

    for (int i = 0; i < L; ++i) {
        layernorm_dual<<<M, 256, 0, stream>>>(h, ln1g + (size_t)i * D, ln1b + (size_t)i * D,
                                              xn_bf, nullptr, D);

        k_gemm_qkv<<<dim3(M / 128, TD / 64), 256, 0, stream>>>(
            xn_bf, wqkvT + (size_t)i * D * TD, bqkv + (size_t)i * TD, qkv_bf,
            M, TD, D, D, D, TD);

        flash_attn<<<dim3(S / 64, BH), 256, 0, stream>>>(qkv_bf, o_bf);

        k_gemm_small<<<dim3(M / 64, D / 64), 256, 0, stream>>>(
            o_bf, woT + (size_t)i * D * D, bo + (size_t)i * D, h,
            M, D, D, D, D, D);

        layernorm_dual<<<M, 256, 0, stream>>>(h, ln2g + (size_t)i * D, ln2b + (size_t)i * D,
                                              xn_bf, nullptr, D);

        k_gemm_fc<<<dim3(M / 128, F / 64), 256, 0, stream>>>(
            xn_bf, wfcT + (size_t)i * D * F, bfc + (size_t)i * F, mid_bf,
            M, F, D, D, D, F);

        k_gemm_small<<<dim3(M / 64, D / 64), 256, 0, stream>>>(
            mid_bf, wprT + (size_t)i * F * D, bpr + (size_t)i * D, h,
            M, D, F, F, F, D);
    }

    layernorm_dual<<<M, 256, 0, stream>>>(h, lnfg, lnfb, hid_bf, hidden, D);

    k_gemm_head<<<dim3(M / 256, NP), 512, 0, stream>>>(
        hid_bf, embB, logits,
        M, V, D, D, D, Vp);

    softmax_vocab<<<M, 256, 0, stream>>>(logits, probs, V, Vp);
}